// Round 1
// 2117.659 us; speedup vs baseline: 1.2458x; 1.2458x over previous
//
#include <hip/hip_runtime.h>

#define TAU 0.25f
#define OMT 0.75f

typedef __attribute__((ext_vector_type(8))) short  bfrag8;   // 8 bf16 = 4 VGPRs (MFMA A/B operand)
typedef __attribute__((ext_vector_type(4))) float  f4acc;    // MFMA C/D
typedef __attribute__((ext_vector_type(4))) float  fvec4;
typedef __attribute__((ext_vector_type(2))) unsigned uvec2;
typedef __attribute__((ext_vector_type(4))) unsigned uvec4;

// d_ws layout (bytes)
#define WS_PACKH 0u         // 32 hps n-tiles * 8 ksteps * 1024B   = 262144
#define WS_PACKS 262144u    // 32 s  n-tiles * 36 ksteps * 1024B   = 1179648
#define WS_PACKC 1441792u   // 8 css n-tiles * 16 ksteps * 1024B   = 131072
#define WS_BIAS  1572864u   // 1152 fp32 (TAU-prescaled), acts-col order

__device__ __forceinline__ unsigned short f2bf(float f) {
    unsigned u = __builtin_bit_cast(unsigned, f);
    u = (u + 0x7FFFu + ((u >> 16) & 1u)) >> 16;   // RNE
    return (unsigned short)u;
}

// ---------------------------------------------------------------------------
// Prep: pack all weights (bf16) into exact MFMA B-fragment stream order.
// (unchanged from previous verified version)
// ---------------------------------------------------------------------------
__global__ void hs04_prep(const float* __restrict__ wph, const float* __restrict__ whs,
                          const float* __restrict__ wss, const float* __restrict__ wsc,
                          const float* __restrict__ wcs, const float* __restrict__ bh,
                          const float* __restrict__ bs,  const float* __restrict__ bc,
                          unsigned char* __restrict__ ws)
{
    int gid = blockIdx.x * 256 + threadIdx.x;
    if (gid < 98304) {                       // 1536 frags * 64 lanes
        int lane = gid & 63, frag = gid >> 6;
        int cls, nt, ks; size_t off;
        if (frag < 256)       { cls = 0; nt = frag >> 3;       ks = frag & 7;
                                off = WS_PACKH + (size_t)nt*8192  + (size_t)ks*1024; }
        else if (frag < 1408) { int f = frag - 256;  cls = 1; nt = f / 36; ks = f - nt*36;
                                off = WS_PACKS + (size_t)nt*36864 + (size_t)ks*1024; }
        else                  { int f = frag - 1408; cls = 2; nt = f >> 4; ks = f & 15;
                                off = WS_PACKC + (size_t)nt*16384 + (size_t)ks*1024; }
        int q = lane >> 4, rr = lane & 15;
        unsigned short v[8];
        #pragma unroll
        for (int j = 0; j < 8; ++j) {
            int k = ks*32 + q*8 + j;
            int n = nt*16 + rr;
            float wv;
            if (cls == 0)      wv = wph[k*512 + n];
            else if (cls == 1) wv = (k < 512)  ? whs[k*512 + n]
                               : (k < 1024) ? wss[(k-512)*512 + n]
                                            : wcs[(k-1024)*512 + n];
            else               wv = wsc[k*128 + n];
            v[j] = f2bf(wv);
        }
        uvec4 pk = { (unsigned)v[0] | ((unsigned)v[1] << 16),
                     (unsigned)v[2] | ((unsigned)v[3] << 16),
                     (unsigned)v[4] | ((unsigned)v[5] << 16),
                     (unsigned)v[6] | ((unsigned)v[7] << 16) };
        *(uvec4*)(ws + off + (size_t)lane*16) = pk;
    } else if (gid < 98304 + 1152) {
        int col = gid - 98304;
        float b = (col < 512) ? bh[col] : (col < 1024 ? bs[col-512] : bc[col-1024]);
        ((float*)(ws + WS_BIAS))[col] = TAU * b;
    }
}

// ---------------------------------------------------------------------------
// Main: 256 persistent blocks * 64 batch rows. Integrator state in MFMA accs.
// This version: explicit 1-deep software pipeline for weight-fragment global
// loads + LDS A-frag loads (latency was the bottleneck: MfmaUtil 9% with all
// pipes <15% busy at 2 waves/SIMD), nontemporal x/out traffic (keep the 1.5 MB
// packed weights L2-resident), leak+bias fused into the epilogue, 5 barriers
// per timestep (was 7) with next-timestep x-tile prefetched under phase 2.
// ---------------------------------------------------------------------------
__global__ __launch_bounds__(512, 2) void hs04_main(const float* __restrict__ x_all,
                                                    const unsigned char* __restrict__ ws,
                                                    float* __restrict__ out)
{
    extern __shared__ char smem[];
    char* const acts = smem;              // 64 rows x 1152 bf16, row stride 2304B, swizzled
    char* const xbuf = smem + 147456;     // 2 x (16 rows x 256 bf16 = 8192B), swizzled

    const int tid  = threadIdx.x;
    const int lane = tid & 63;
    const int wu   = __builtin_amdgcn_readfirstlane(tid >> 6);   // wave id -> SGPR
    const int q    = lane >> 4;
    const int r    = lane & 15;
    const int b0   = blockIdx.x << 6;

    // init acts = bf16(TAU*0.5) everywhere (value-uniform -> swizzle irrelevant)
    {
        unsigned hv = f2bf(0.125f);
        unsigned u  = hv | (hv << 16);
        uvec4 fill = {u, u, u, u};
        uvec4* p = (uvec4*)acts;
        for (int i = tid; i < 9216; i += 512) p[i] = fill;
    }

    float tb[9];
    {
        const float* bias = (const float*)(ws + WS_BIAS);
        #pragma unroll
        for (int j = 0; j < 9; ++j) {
            int cb = (j < 4) ? wu*64 + j*16 : (j < 8) ? 512 + wu*64 + (j-4)*16 : 1024 + wu*16;
            tb[j] = bias[cb + r];
        }
    }

    // acc == integrator value `in`; init = TAU*bias (== OMT*0 + tb, leak fused in epilogue)
    f4acc acc[9][4];
    #pragma unroll
    for (int j = 0; j < 9; ++j) {
        float tbj = tb[j];
        #pragma unroll
        for (int m = 0; m < 4; ++m) acc[j][m] = {tbj, tbj, tbj, tbj};
    }

    const bfrag8* bHp[4]; const bfrag8* bSp[4]; const bfrag8* bCp;
    #pragma unroll
    for (int j = 0; j < 4; ++j) {
        bHp[j] = (const bfrag8*)(ws + WS_PACKH + (size_t)(wu*4+j)*8192)  + lane;
        bSp[j] = (const bfrag8*)(ws + WS_PACKS + (size_t)(wu*4+j)*36864) + lane;
    }
    bCp = (const bfrag8*)(ws + WS_PACKC + (size_t)wu*16384) + lane;

    // ---- staging helpers (T14 split: issue loads early, LDS-write late) ----
    auto stageX_load = [&](const float* xt, int mt, fvec4 (&v)[2]) {
        const fvec4* src = (const fvec4*)xt + (size_t)mt*1024;
        v[0] = __builtin_nontemporal_load(src + tid);
        v[1] = __builtin_nontemporal_load(src + tid + 512);
    };
    auto stageX_write = [&](const fvec4 (&v)[2], char* dst) {
        #pragma unroll
        for (int i = 0; i < 2; ++i) {
            int f4i = tid + i*512;
            int row = f4i >> 6, c4 = f4i & 63;
            unsigned lo = (unsigned)f2bf(TAU*v[i].x) | ((unsigned)f2bf(TAU*v[i].y) << 16);
            unsigned hi = (unsigned)f2bf(TAU*v[i].z) | ((unsigned)f2bf(TAU*v[i].w) << 16);
            uvec2 d = {lo, hi};
            *(uvec2*)(dst + row*512 + (((c4 >> 1) ^ row) << 4) + ((c4 & 1) << 3)) = d;
        }
    };
    auto loadBS = [&](int ks, bfrag8 (&d)[4]) {
        #pragma unroll
        for (int j = 0; j < 4; ++j) d[j] = bSp[j][ks*64];
    };
    auto loadA2 = [&](int ks, bfrag8 (&d)[4]) {
        const char* p = acts + r*2304 + ((((ks << 2) + q) ^ r) << 4);
        #pragma unroll
        for (int m = 0; m < 4; ++m) d[m] = *(const bfrag8*)(p + m*36864);
    };
    auto mm16 = [&](bfrag8 (&a)[4], bfrag8 (&b)[4]) {
        #pragma unroll
        for (int j = 0; j < 4; ++j)
            #pragma unroll
            for (int m = 0; m < 4; ++m)
                acc[4+j][m] = __builtin_amdgcn_mfma_f32_16x16x32_bf16(a[m], b[j], acc[4+j][m], 0, 0, 0);
    };
    auto mmc = [&](bfrag8 (&a)[4], bfrag8 c) {
        #pragma unroll
        for (int m = 0; m < 4; ++m)
            acc[8][m] = __builtin_amdgcn_mfma_f32_16x16x32_bf16(a[m], c, acc[8][m], 0, 0, 0);
    };

    // prologue: stage x(t=0, mt=0) into xbuf half 0
    {
        fvec4 xv0[2];
        stageX_load(x_all + (size_t)b0*256, 0, xv0);
        stageX_write(xv0, xbuf);
    }
    __syncthreads();

    for (int t = 0; t < 20; ++t) {
        const float* xt = x_all + ((size_t)t*16384 + (size_t)b0)*256;
        fvec4 xv[2];

        // ---- phase 1: hps GEMM, x staged 16 rows/chunk, B ping-pong pipelined
        #pragma unroll
        for (int mt = 0; mt < 4; ++mt) {
            if (mt < 3) stageX_load(xt, mt+1, xv);        // issue early, write late
            const char* xb = xbuf + (mt & 1)*8192;
            bfrag8 hb0[4], hb1[4];
            #pragma unroll
            for (int j = 0; j < 4; ++j) hb0[j] = bHp[j][0];
            #pragma unroll 1
            for (int k2 = 0; k2 < 8; k2 += 2) {
                #pragma unroll
                for (int j = 0; j < 4; ++j) hb1[j] = bHp[j][(k2+1)*64];
                {
                    bfrag8 ha = *(const bfrag8*)(xb + r*512 + ((((k2 << 2) + q) ^ r) << 4));
                    #pragma unroll
                    for (int j = 0; j < 4; ++j)
                        acc[j][mt] = __builtin_amdgcn_mfma_f32_16x16x32_bf16(ha, hb0[j], acc[j][mt], 0, 0, 0);
                }
                if (k2 + 2 < 8) {
                    #pragma unroll
                    for (int j = 0; j < 4; ++j) hb0[j] = bHp[j][(k2+2)*64];
                }
                {
                    bfrag8 ha = *(const bfrag8*)(xb + r*512 + (((((k2+1) << 2) + q) ^ r) << 4));
                    #pragma unroll
                    for (int j = 0; j < 4; ++j)
                        acc[j][mt] = __builtin_amdgcn_mfma_f32_16x16x32_bf16(ha, hb1[j], acc[j][mt], 0, 0, 0);
                }
            }
            if (mt < 3) {
                stageX_write(xv, xbuf + ((mt+1) & 1)*8192);  // vmcnt wait lands here
                __syncthreads();
            }
            // mt==3: no barrier needed — phase 2 touches only acts (synced last t),
            // and the phase-2 x prefetch writes the other xbuf half.
        }

        // ---- phase 2: s + css GEMM over acts, 1-deep ping-pong pipeline
        {
            bfrag8 sa0[4], sa1[4], sb0[4], sb1[4];
            loadBS(0, sb0); loadA2(0, sa0);
            #pragma unroll 1
            for (int ks = 0; ks < 16; ks += 2) {           // no css
                loadBS(ks+1, sb1); loadA2(ks+1, sa1);
                mm16(sa0, sb0);
                loadBS(ks+2, sb0); loadA2(ks+2, sa0);
                mm16(sa1, sb1);
            }
            #pragma unroll 1
            for (int ks = 16; ks < 32; ks += 2) {          // with css (k 512..1023)
                bfrag8 c0 = bCp[(ks-16)*64];               // self-hides behind 16 MFMAs
                loadBS(ks+1, sb1); loadA2(ks+1, sa1);
                mm16(sa0, sb0);
                mmc(sa0, c0);
                bfrag8 c1 = bCp[(ks-15)*64];
                loadBS(ks+2, sb0); loadA2(ks+2, sa0);
                mm16(sa1, sb1);
                mmc(sa1, c1);
            }
            if (t < 19) stageX_load(xt + 16384*256, 0, xv);  // next-t mt=0, hides under tail
            #pragma unroll 1
            for (int ks = 32; ks < 36; ks += 2) {
                loadBS(ks+1, sb1); loadA2(ks+1, sa1);
                mm16(sa0, sb0);
                if (ks + 2 < 36) { loadBS(ks+2, sb0); loadA2(ks+2, sa0); }
                mm16(sa1, sb1);
            }
            if (t < 19) stageX_write(xv, xbuf);            // xbuf half 0, read next t after 2 barriers
        }

        // ---- phase 3: sigmoid -> new acts + fused leak/bias + output ticks
        __syncthreads();    // all reads of old acts complete
        {
            const bool emit = (t >= 16);
            #pragma unroll
            for (int j = 0; j < 9; ++j) {
                int cb = (j < 4) ? wu*64 + j*16 : (j < 8) ? 512 + wu*64 + (j-4)*16 : 1024 + wu*16;
                int col   = cb + r;               // C/D layout: col = lane&15
                int chunk = col >> 3;
                int coff  = (col & 7) << 1;
                float tbj = tb[j];
                #pragma unroll
                for (int m = 0; m < 4; ++m) {
                    f4acc v = acc[j][m];
                    #pragma unroll
                    for (int e = 0; e < 4; ++e) {
                        int rl  = q*4 + e;        // C/D layout: row = quad*4 + reg
                        int row = m*16 + rl;
                        float in = v[e];
                        float a  = 1.0f / (1.0f + __expf(-in));
                        *(unsigned short*)(acts + row*2304 + ((chunk ^ rl) << 4) + coff) = f2bf(TAU * a);
                        if (emit && j >= 4 && j < 8) {
                            __builtin_nontemporal_store(
                                a, out + ((size_t)(t-16)*16384 + (size_t)(b0 + row))*512 + (col - 512));
                        }
                    }
                    acc[j][m] = v*OMT + tbj;      // fused leak + bias for next timestep
                }
            }
        }
        __syncthreads();    // new acts (and xbuf half 0) visible before next timestep
    }
}

extern "C" void kernel_launch(void* const* d_in, const int* in_sizes, int n_in,
                              void* d_out, int out_size, void* d_ws, size_t ws_size,
                              hipStream_t stream) {
    const float* x   = (const float*)d_in[0];
    const float* wph = (const float*)d_in[1];
    const float* whs = (const float*)d_in[2];
    const float* wss = (const float*)d_in[3];
    const float* wsc = (const float*)d_in[4];
    const float* wcs = (const float*)d_in[5];
    const float* bh  = (const float*)d_in[6];
    const float* bs  = (const float*)d_in[7];
    const float* bc  = (const float*)d_in[8];
    unsigned char* ws = (unsigned char*)d_ws;
    float* outp = (float*)d_out;

    hipFuncSetAttribute((const void*)hs04_main,
                        hipFuncAttributeMaxDynamicSharedMemorySize, 163840);

    hipLaunchKernelGGL(hs04_prep, dim3(389), dim3(256), 0, stream,
                       wph, whs, wss, wsc, wcs, bh, bs, bc, ws);
    hipLaunchKernelGGL(hs04_main, dim3(256), dim3(512), 163840, stream,
                       x, ws, outp);
}